// Round 16
// baseline (284.851 us; speedup 1.0000x reference)
//
#include <hip/hip_runtime.h>
#include <hip/hip_bf16.h>
#include <stdint.h>

// ---------------------------------------------------------------------------
// ChebConv with attention + per-(t,k) dropout, MI355X bf16 MFMA implementation
// out[b,t,u,o] = relu( sum_k M[t,k] @ (x[b,t] @ Theta[k]) )
// mask = threefry2x32 partitionable, key(42), bits = x0^x1   (verified R0)
// B=32 T=12 V=1000(pad 1024) F=O=64 K=3
//
// R16: ZERO-LDS, ZERO-BARRIER K-loop. Both operands are pre-laid-out in MFMA
// fragment order in ws (Mf: R11-verified; xtf: new, same bijection family),
// so every A/B fragment is ONE coalesced 1KB global_load_dwordx4 to VGPRs.
// R15 sat exactly at the LDS(937cy) == MFMA(932cy) balance point per chunk;
// barriers+single-buffer dragged it to 35% MfmaUtil. Now: LDS ~0, L2 ~714cy,
// MFMA 932cy -> MFMA-bound; 8 free-running waves/CU provide TLP (m114).
// B-frag register reuse keeps the 3-slab fusion (pacc[3] in AGPRs).
// XCD swizzle nt-fastest: A slab (384KB) shared per XCD; B panels via L3.
// Stage-2 (P_k @ ThetaT[k]) keeps R15's verified LDS path (13.8KB).
// ws: Mf [36<<20] bf16 frag-order (75.5MB) | xtf [12*128*32*512] bf16 (50.3MB)
// ---------------------------------------------------------------------------

typedef __attribute__((ext_vector_type(8))) short short8;
typedef __attribute__((ext_vector_type(4))) float f32x4;

__device__ __forceinline__ ushort f2bf(float f) {
  __hip_bfloat16 h = __float2bfloat16(f);
  return *reinterpret_cast<ushort*>(&h);
}

__device__ __forceinline__ void threefry2x32(uint32_t c0, uint32_t c1,
                                             uint32_t& o0, uint32_t& o1) {
  const uint32_t ks0 = 0u;
  const uint32_t ks1 = 42u;
  const uint32_t ks2 = ks0 ^ ks1 ^ 0x1BD11BDAu;
  uint32_t x0 = c0 + ks0;
  uint32_t x1 = c1 + ks1;
#define TFR(r) { x0 += x1; x1 = (x1 << (r)) | (x1 >> (32 - (r))); x1 ^= x0; }
  TFR(13) TFR(15) TFR(26) TFR(6)
  x0 += ks1; x1 += ks2 + 1u;
  TFR(17) TFR(29) TFR(16) TFR(24)
  x0 += ks2; x1 += ks0 + 2u;
  TFR(13) TFR(15) TFR(26) TFR(6)
  x0 += ks0; x1 += ks1 + 3u;
  TFR(17) TFR(29) TFR(16) TFR(24)
  x0 += ks1; x1 += ks2 + 4u;
  TFR(13) TFR(15) TFR(26) TFR(6)
  x0 += ks2; x1 += ks0 + 5u;
#undef TFR
  o0 = x0; o1 = x1;
}

// ---------------------------------------------------------------------------
// Kernel 1: build masked M (bf16) in MFMA-fragment order (R11-verified).
// idx = (((tk*64+u16)*16+vc)*2+ks)*512 + lane*8 + j;
// u = u16*16+(lane&15), v = vc*64+ks*32+(lane>>4)*8+j.
// ---------------------------------------------------------------------------
__global__ void build_m(const float* __restrict__ Att,
                        const float* __restrict__ cheb,
                        ushort* __restrict__ Mf) {
  const uint32_t idx = blockIdx.x * 256u + threadIdx.x;
  const uint32_t j = idx & 7u;
  const uint32_t lane = (idx >> 3) & 63u;
  const uint32_t ks = (idx >> 9) & 1u;
  const uint32_t c = (idx >> 10) & 15u;
  const uint32_t u16 = (idx >> 14) & 63u;
  const uint32_t tk = idx >> 20;
  const uint32_t up = u16 * 16u + (lane & 15u);
  const uint32_t vp = c * 64u + ks * 32u + (lane >> 4) * 8u + j;
  float val = 0.f;
  if ((vp < 1000u) & (up < 1000u)) {
    const uint32_t flat = (tk * 1000u + up) * 1000u + vp;
    uint32_t o0, o1;
    threefry2x32(0u, flat, o0, o1);
    const uint32_t bits = o0 ^ o1;
    const float u = __uint_as_float((bits >> 9) | 0x3f800000u) - 1.0f;
    if (u < 0.4f) {
      val = cheb[(tk % 3u) * 1000000u + up * 1000u + vp] *
            Att[up * 1000u + vp] * 2.5f;
    }
  }
  Mf[idx] = f2bf(val);
}

// ---------------------------------------------------------------------------
// Kernel 2: xtf fragment-order build from x.
// B-frag(t, n16, vc, ks) element (lane, j) = x-transposed[n = n16*16+(lane&15)]
//   [v = vc*64 + ks*32 + (lane>>4)*8 + j],  n = b*64 + f.
// Same LDS transpose as before; only the final store addresses change:
//   uint4 of (n, vv..vv+7):  frag = (t, n>>4, vv>>6, (vv>>5)&1),
//   lane = (f&15) + 16*((vv&31)>>3), elem = frag*512 + lane*8.
// ---------------------------------------------------------------------------
__global__ void transpose_x(const float* __restrict__ x,
                            ushort* __restrict__ xtf) {
  __shared__ float lt[64][65];
  const int vc = blockIdx.x, t = blockIdx.y, b = blockIdx.z;
  const int tid = threadIdx.x;
  const int v0 = vc * 64;
#pragma unroll
  for (int i = 0; i < 4; ++i) {
    const int c = i * 256 + tid;
    const int vi = c >> 4, f4 = c & 15;
    float4 q = make_float4(0.f, 0.f, 0.f, 0.f);
    if (v0 + vi < 1000)
      q = *(const float4*)(x + ((((size_t)b * 12 + t) * 1000 + v0 + vi) << 6) + f4 * 4);
    lt[f4 * 4 + 0][vi] = q.x;
    lt[f4 * 4 + 1][vi] = q.y;
    lt[f4 * 4 + 2][vi] = q.z;
    lt[f4 * 4 + 3][vi] = q.w;
  }
  __syncthreads();
  const int f = tid >> 2, g = tid & 3;   // f 0..63, g = 16-v segment
  alignas(16) ushort tmp[16];
#pragma unroll
  for (int j = 0; j < 16; ++j) tmp[j] = f2bf(lt[f][g * 16 + j]);
  // fragment-order store
  const int n16 = b * 4 + (f >> 4);
  const int ks = g >> 1;
  const int l0 = (f & 15) + 16 * ((g & 1) * 2);   // lane for first uint4
  const size_t fb = ((((size_t)(t * 128 + n16) * 16 + vc) * 2 + ks) << 9);
  *(uint4*)(xtf + fb + (size_t)l0 * 8)        = *(const uint4*)&tmp[0];
  *(uint4*)(xtf + fb + (size_t)(l0 + 16) * 8) = *(const uint4*)&tmp[8];
}

// ---------------------------------------------------------------------------
// Kernel 3: main fused GEMM, zero-LDS zero-barrier K-loop.
// 256 thr (4 waves, 2x2), block 64u x 128n per t, wave tile 32u x 64n.
// Per 64-chunk: 12 A-frags + 8 B-frags, each ONE coalesced 1KB load; B-frag
// reused across 3 k in regs; 48 MFMA into pacc[3] (AGPR).
// Stage 2 (R15-verified): pacc[k] -> sP(bf16) -> oacc += P @ ThetaT[k].
// Grid 3072 1D, XCD-bijective, nt-fastest (A slab shared per XCD).
// ---------------------------------------------------------------------------
#define LDT 72
#define MFMA(a, b, c) __builtin_amdgcn_mfma_f32_16x16x32_bf16((a), (b), (c), 0, 0, 0)

__global__ __launch_bounds__(256, 2)
void cheb_main(const ushort* __restrict__ Mf, const ushort* __restrict__ xtf,
               const float* __restrict__ Theta, float* __restrict__ out) {
  __shared__ __align__(16) ushort smem[13824];  // stage-2 only: sP | sTh
  const int tid = threadIdx.x;
  const int lane = tid & 63;
  const int w = tid >> 6;              // wave 0..3
  const int wu = w >> 1, wn = w & 1;   // wave tile: u = wu*32, n = wn*64
  const int quad = lane >> 4, l15 = lane & 15;

  // XCD-bijective decode (3072 % 8 == 0), nt-fastest within each XCD chunk
  const int bid = blockIdx.x;
  const int swz = (bid & 7) * 384 + (bid >> 3);
  const int nt = swz & 15;
  const int g = swz >> 4;              // 0..191
  const int ut = g & 15;
  const int t = g >> 4;                // 0..11
  const int u0 = ut * 64, n0 = nt * 128;

  // fragment base addresses (element offsets; +vc*1024 + ks*512 per chunk)
  // A frag(tk, u16, vc, ks): base = ((tk*64+u16)*32) << 9
  size_t fA[3][2];
#pragma unroll
  for (int k = 0; k < 3; ++k)
#pragma unroll
    for (int mi = 0; mi < 2; ++mi)
      fA[k][mi] = (((size_t)((t * 3 + k) * 64 + ut * 4 + wu * 2 + mi)) << 14)
                  + (size_t)lane * 8;
  // B frag(t, n16, vc, ks): base = ((t*128+n16)*32) << 9
  size_t fB[4];
#pragma unroll
  for (int ni = 0; ni < 4; ++ni)
    fB[ni] = (((size_t)(t * 128 + nt * 8 + wn * 4 + ni)) << 14)
             + (size_t)lane * 8;

  f32x4 pacc[3][2][4];
#pragma unroll
  for (int k = 0; k < 3; ++k)
#pragma unroll
    for (int i = 0; i < 2; ++i)
#pragma unroll
      for (int j = 0; j < 4; ++j) pacc[k][i][j] = f32x4{0.f, 0.f, 0.f, 0.f};

  // ---- main K loop: 16 chunks of 64, no LDS, no barriers ----
#pragma unroll 1
  for (int vc = 0; vc < 16; ++vc) {
    const size_t co = (size_t)vc << 10;
    short8 a[3][2][2], b[4][2];
#pragma unroll
    for (int ni = 0; ni < 4; ++ni)
#pragma unroll
      for (int ks = 0; ks < 2; ++ks)
        b[ni][ks] = *(const short8*)(xtf + fB[ni] + co + ((size_t)ks << 9));
#pragma unroll
    for (int k = 0; k < 3; ++k)
#pragma unroll
      for (int mi = 0; mi < 2; ++mi)
#pragma unroll
        for (int ks = 0; ks < 2; ++ks)
          a[k][mi][ks] = *(const short8*)(Mf + fA[k][mi] + co + ((size_t)ks << 9));
    __builtin_amdgcn_s_setprio(1);
#pragma unroll
    for (int ks = 0; ks < 2; ++ks)
#pragma unroll
      for (int k = 0; k < 3; ++k)
#pragma unroll
        for (int mi = 0; mi < 2; ++mi)
#pragma unroll
          for (int ni = 0; ni < 4; ++ni)
            pacc[k][mi][ni] = MFMA(a[k][mi][ks], b[ni][ks], pacc[k][mi][ni]);
    __builtin_amdgcn_s_setprio(0);
  }

  // ---- stage 2: oacc += P_k @ ThetaT[k], k fully unrolled (R15-verified) ----
  ushort* sP  = smem + w * 2304;       // 32 x 72, wave-local
  ushort* sTh = smem + 9216;           // 64 x 72
  f32x4 oacc[2][4];
#pragma unroll
  for (int i = 0; i < 2; ++i)
#pragma unroll
    for (int j = 0; j < 4; ++j) oacc[i][j] = f32x4{0.f, 0.f, 0.f, 0.f};

#pragma unroll
  for (int k = 0; k < 3; ++k) {
    __syncthreads();  // prev readers done
#pragma unroll
    for (int mi = 0; mi < 2; ++mi)
#pragma unroll
      for (int ni = 0; ni < 4; ++ni)
#pragma unroll
        for (int r = 0; r < 4; ++r)
          sP[(mi * 16 + quad * 4 + r) * LDT + ni * 16 + l15] = f2bf(pacc[k][mi][ni][r]);
    for (int e = tid; e < 4096; e += 256) {
      const int f = e >> 6, o = e & 63;
      sTh[o * LDT + f] = f2bf(Theta[k * 4096 + e]);
    }
    __syncthreads();
#pragma unroll
    for (int ks = 0; ks < 2; ++ks) {
      short8 a2[2], b2[4];
#pragma unroll
      for (int mi = 0; mi < 2; ++mi)
        a2[mi] = *(const short8*)&sP[(mi * 16 + l15) * LDT + ks * 32 + quad * 8];
#pragma unroll
      for (int ni = 0; ni < 4; ++ni)
        b2[ni] = *(const short8*)&sTh[(ni * 16 + l15) * LDT + ks * 32 + quad * 8];
#pragma unroll
      for (int mi = 0; mi < 2; ++mi)
#pragma unroll
        for (int ni = 0; ni < 4; ++ni)
          oacc[mi][ni] = MFMA(a2[mi], b2[ni], oacc[mi][ni]);
    }
  }

  // ---- epilogue: relu + store ----
#pragma unroll
  for (int mi = 0; mi < 2; ++mi) {
    const int u_base = u0 + wu * 32 + mi * 16 + quad * 4;
#pragma unroll
    for (int ni = 0; ni < 4; ++ni) {
      const int n = n0 + wn * 64 + ni * 16 + l15;
      const int b = n >> 6, oo = n & 63;
      float* op = out + (((size_t)b * 12 + t) * 1000) * 64 + oo;
#pragma unroll
      for (int r = 0; r < 4; ++r) {
        const int u = u_base + r;
        if (u < 1000) op[(size_t)u * 64] = fmaxf(oacc[mi][ni][r], 0.f);
      }
    }
  }
}

// ---------------------------------------------------------------------------
extern "C" void kernel_launch(void* const* d_in, const int* in_sizes, int n_in,
                              void* d_out, int out_size, void* d_ws, size_t ws_size,
                              hipStream_t stream) {
  const float* x     = (const float*)d_in[0];
  const float* Att   = (const float*)d_in[1];
  const float* cheb  = (const float*)d_in[2];
  const float* Theta = (const float*)d_in[3];
  float* out = (float*)d_out;

  ushort* Mf  = (ushort*)d_ws;                 // 36*1024*1024 bf16, frag order
  ushort* xtf = Mf + 37748736ull;              // 12*128*16*2*512 bf16, frag order
  // requires ws_size >= 125,829,120 bytes (proven budget)

  build_m<<<147456, 256, 0, stream>>>(Att, cheb, Mf);
  transpose_x<<<dim3(16, 12, 32), 256, 0, stream>>>(x, xtf);
  cheb_main<<<3072, 256, 0, stream>>>(Mf, xtf, Theta, out);
}